// Round 1
// baseline (6160.876 us; speedup 1.0000x reference)
//
#include <hip/hip_runtime.h>
#include <hip/hip_bf16.h>
#include <math.h>

// Problem constants
#define BB   2
#define LL   1024
#define DD   768
#define DIN  1536      // d_inner
#define NS   16        // d_state
#define DCV  4         // d_conv
#define DTRK 48        // dt_rank
#define NLAY 4
#define VV   32000
#define ROWS (BB*LL)   // 2048

// ---------------- elementwise / small kernels ----------------

__global__ __launch_bounds__(256) void embed_kernel(
    const int* __restrict__ tok, const float* __restrict__ emb,
    float* __restrict__ x) {
  int idx = blockIdx.x * 256 + threadIdx.x;          // 2048*768 total
  int row = idx / DD, c = idx - row * DD;
  x[idx] = emb[(size_t)tok[row] * DD + c];
}

__global__ __launch_bounds__(256) void rmsnorm_kernel(
    const float* __restrict__ x, const float* __restrict__ w,
    float* __restrict__ xn) {
  int row = blockIdx.x;
  int t = threadIdx.x;
  const float* xr = x + (size_t)row * DD;
  float v0 = xr[t], v1 = xr[t + 256], v2 = xr[t + 512];
  float ss = v0 * v0 + v1 * v1 + v2 * v2;
#pragma unroll
  for (int off = 32; off > 0; off >>= 1) ss += __shfl_down(ss, off);
  __shared__ float sred[4];
  if ((t & 63) == 0) sred[t >> 6] = ss;
  __syncthreads();
  float tot = sred[0] + sred[1] + sred[2] + sred[3];
  float scale = rsqrtf(tot * (1.0f / DD) + 1e-5f);
  float* xo = xn + (size_t)row * DD;
  xo[t]       = v0 * scale * w[t];
  xo[t + 256] = v1 * scale * w[t + 256];
  xo[t + 512] = v2 * scale * w[t + 512];
}

// causal depthwise conv (DC=4) + bias + silu; input = first DIN cols of xz
__global__ __launch_bounds__(256) void conv_silu_kernel(
    const float* __restrict__ xz, const float* __restrict__ cw,
    const float* __restrict__ cb, float* __restrict__ xb) {
  int idx = blockIdx.x * 256 + threadIdx.x;          // 2048*1536 total
  int row = idx / DIN;                               // b*L + l
  int d = idx - row * DIN;
  int l = row & (LL - 1);
  const float* col = xz + (size_t)row * (2 * DIN) + d;
  float w0 = cw[d * 4 + 0], w1 = cw[d * 4 + 1], w2 = cw[d * 4 + 2],
        w3 = cw[d * 4 + 3];
  float acc = cb[d] + w3 * col[0];
  if (l >= 1) acc += w2 * col[-(2 * DIN)];
  if (l >= 2) acc += w1 * col[-2 * (2 * DIN)];
  if (l >= 3) acc += w0 * col[-3 * (2 * DIN)];
  float sig = 1.0f / (1.0f + __expf(-acc));
  xb[idx] = acc * sig;
}

// ---------------- GEMM: C(M x N) = A(M x K) * W(N x K)^T ----------------
// EPI: 0 = none, 1 = softplus(acc + bias[n]), 2 = C += acc (residual),
//      3 = acc + bias[n]
__device__ __forceinline__ float softplus_f(float t) {
  return t > 20.0f ? t : log1pf(__expf(t));
}

template <int EPI>
__global__ __launch_bounds__(256) void sgemm_nt(
    const float* __restrict__ A, int lda,
    const float* __restrict__ W, int ldw,
    float* __restrict__ C, int ldc,
    int N, int K, const float* __restrict__ bias) {
  __shared__ float As[16][68];
  __shared__ float Ws[16][68];
  const int tid = threadIdx.x;
  const int tx = tid & 15, ty = tid >> 4;
  const int bm = blockIdx.x, bn = blockIdx.y;
  const int lrow = tid >> 2;          // 0..63
  const int lk4 = (tid & 3) << 2;     // 0,4,8,12
  const float* Aptr = A + (size_t)(bm * 64 + lrow) * lda + lk4;
  const int wrow = bn * 64 + lrow;
  const float* Wptr = W + (size_t)wrow * ldw + lk4;
  const bool wvalid = wrow < N;
  float c[4][4] = {};
  for (int k0 = 0; k0 < K; k0 += 16) {
    float4 a4 = *(const float4*)(Aptr + k0);
    float4 w4 = wvalid ? *(const float4*)(Wptr + k0) : make_float4(0, 0, 0, 0);
    __syncthreads();
    As[lk4 + 0][lrow] = a4.x; As[lk4 + 1][lrow] = a4.y;
    As[lk4 + 2][lrow] = a4.z; As[lk4 + 3][lrow] = a4.w;
    Ws[lk4 + 0][lrow] = w4.x; Ws[lk4 + 1][lrow] = w4.y;
    Ws[lk4 + 2][lrow] = w4.z; Ws[lk4 + 3][lrow] = w4.w;
    __syncthreads();
#pragma unroll
    for (int k = 0; k < 16; k++) {
      float4 a = *(const float4*)&As[k][ty << 2];
      float4 w = *(const float4*)&Ws[k][tx << 2];
      c[0][0] += a.x * w.x; c[0][1] += a.x * w.y; c[0][2] += a.x * w.z; c[0][3] += a.x * w.w;
      c[1][0] += a.y * w.x; c[1][1] += a.y * w.y; c[1][2] += a.y * w.z; c[1][3] += a.y * w.w;
      c[2][0] += a.z * w.x; c[2][1] += a.z * w.y; c[2][2] += a.z * w.z; c[2][3] += a.z * w.w;
      c[3][0] += a.w * w.x; c[3][1] += a.w * w.y; c[3][2] += a.w * w.z; c[3][3] += a.w * w.w;
    }
  }
  const int m0 = bm * 64 + (ty << 2);
  const int n0 = bn * 64 + (tx << 2);
#pragma unroll
  for (int i = 0; i < 4; i++) {
    float* crow = C + (size_t)(m0 + i) * ldc;
    if (n0 + 3 < N) {
      float4 r;
      if constexpr (EPI == 0) {
        r = make_float4(c[i][0], c[i][1], c[i][2], c[i][3]);
      } else if constexpr (EPI == 1) {
        r = make_float4(softplus_f(c[i][0] + bias[n0 + 0]),
                        softplus_f(c[i][1] + bias[n0 + 1]),
                        softplus_f(c[i][2] + bias[n0 + 2]),
                        softplus_f(c[i][3] + bias[n0 + 3]));
      } else if constexpr (EPI == 2) {
        float4 o = *(const float4*)(crow + n0);
        r = make_float4(o.x + c[i][0], o.y + c[i][1], o.z + c[i][2],
                        o.w + c[i][3]);
      } else {
        r = make_float4(c[i][0] + bias[n0 + 0], c[i][1] + bias[n0 + 1],
                        c[i][2] + bias[n0 + 2], c[i][3] + bias[n0 + 3]);
      }
      *(float4*)(crow + n0) = r;
    } else {
      for (int j = 0; j < 4; j++) {
        int n = n0 + j;
        if (n < N) {
          float v = c[i][j];
          if constexpr (EPI == 1) v = softplus_f(v + bias[n]);
          else if constexpr (EPI == 2) v = crow[n] + v;
          else if constexpr (EPI == 3) v = v + bias[n];
          crow[n] = v;
        }
      }
    }
  }
}

// ---------------- selective scan ----------------
// One wave handles 4 channels (sub=lane/16), 16 states each (n=lane%16).
__global__ __launch_bounds__(256) void scan_kernel(
    const float* __restrict__ u,      // xb   (2048 x 1536)
    const float* __restrict__ dlt,    // delta(2048 x 1536)
    const float* __restrict__ xdbl,   // (2048 x 80): B at +48, C at +64
    const float* __restrict__ xz,     // z at col DIN+d, stride 2*DIN
    const float* __restrict__ A_log,  // layer slice (1536 x 16)
    const float* __restrict__ Dv,     // layer slice (1536)
    float* __restrict__ y) {          // (2048 x 1536)
  int tid = blockIdx.x * 256 + threadIdx.x;
  int lane = threadIdx.x & 63;
  int n = lane & 15;
  int sub = lane >> 4;
  int wv = tid >> 6;                  // global wave id, 0..767
  int p = wv * 4 + sub;               // 0..3071 (b,d) pair
  int b = p / DIN;
  int d = p - b * DIN;
  float Ac = -__expf(A_log[d * NS + n]);
  float Dd = Dv[d];
  const float* urow = u + (size_t)b * LL * DIN + d;
  const float* drow = dlt + (size_t)b * LL * DIN + d;
  const float* brow = xdbl + (size_t)b * LL * 80 + DTRK + n;
  const float* crow = xdbl + (size_t)b * LL * 80 + DTRK + NS + n;
  const float* zrow = xz + (size_t)b * LL * (2 * DIN) + DIN + d;
  float* yrow = y + (size_t)b * LL * DIN + d;
  float h = 0.0f;
  for (int l = 0; l < LL; l++) {
    float dl = drow[(size_t)l * DIN];
    float ul = urow[(size_t)l * DIN];
    float bl = brow[(size_t)l * 80];
    float cl = crow[(size_t)l * 80];
    h = __expf(dl * Ac) * h + dl * bl * ul;
    float yp = h * cl;
    yp += __shfl_xor(yp, 1);
    yp += __shfl_xor(yp, 2);
    yp += __shfl_xor(yp, 4);
    yp += __shfl_xor(yp, 8);
    if (n == 0) {
      float z = zrow[(size_t)l * (2 * DIN)];
      float sig = 1.0f / (1.0f + __expf(-z));
      yrow[(size_t)l * DIN] = (yp + ul * Dd) * (z * sig);
    }
  }
}

// ---------------- launch ----------------

extern "C" void kernel_launch(void* const* d_in, const int* in_sizes, int n_in,
                              void* d_out, int out_size, void* d_ws,
                              size_t ws_size, hipStream_t stream) {
  const int*   tokens    = (const int*)d_in[0];
  const float* embedding = (const float*)d_in[1];
  const float* W_out_w   = (const float*)d_in[2];
  const float* W_out_b   = (const float*)d_in[3];
  const float* norm_w    = (const float*)d_in[4];
  const float* in_proj_w = (const float*)d_in[5];
  const float* conv_w    = (const float*)d_in[6];
  const float* conv_b    = (const float*)d_in[7];
  const float* x_proj_w  = (const float*)d_in[8];
  const float* dt_proj_w = (const float*)d_in[9];
  const float* dt_proj_b = (const float*)d_in[10];
  const float* A_log     = (const float*)d_in[11];
  const float* Dvec      = (const float*)d_in[12];
  const float* out_proj_w= (const float*)d_in[13];
  float* out = (float*)d_out;

  float* ws = (float*)d_ws;
  float* x    = ws;                        // 2048*768
  float* xn   = x + (size_t)ROWS * DD;     // 2048*768
  float* xz   = xn + (size_t)ROWS * DD;    // 2048*3072
  float* xb   = xz + (size_t)ROWS * 2 * DIN;   // 2048*1536
  float* xdbl = xb + (size_t)ROWS * DIN;   // 2048*80
  float* dlt  = xdbl + (size_t)ROWS * 80;  // 2048*1536
  float* yb   = dlt + (size_t)ROWS * DIN;  // 2048*1536

  embed_kernel<<<ROWS * DD / 256, 256, 0, stream>>>(tokens, embedding, x);

  for (int i = 0; i < NLAY; i++) {
    rmsnorm_kernel<<<ROWS, 256, 0, stream>>>(x, norm_w + (size_t)i * DD, xn);
    // xz = xn @ in_proj^T   (2048x768)x(3072x768)^T
    sgemm_nt<0><<<dim3(32, 48), 256, 0, stream>>>(
        xn, DD, in_proj_w + (size_t)i * 2 * DIN * DD, DD, xz, 2 * DIN,
        2 * DIN, DD, nullptr);
    // xb = silu(conv(xz[:, :DIN]))
    conv_silu_kernel<<<ROWS * DIN / 256, 256, 0, stream>>>(
        xz, conv_w + (size_t)i * DIN * DCV, conv_b + (size_t)i * DIN, xb);
    // x_dbl = xb @ x_proj^T (2048x1536)x(80x1536)^T
    sgemm_nt<0><<<dim3(32, 2), 256, 0, stream>>>(
        xb, DIN, x_proj_w + (size_t)i * (DTRK + 2 * NS) * DIN, DIN, xdbl,
        DTRK + 2 * NS, DTRK + 2 * NS, DIN, nullptr);
    // delta = softplus(dt @ dt_proj^T + dt_b) (2048x48)x(1536x48)^T
    sgemm_nt<1><<<dim3(32, 24), 256, 0, stream>>>(
        xdbl, DTRK + 2 * NS, dt_proj_w + (size_t)i * DIN * DTRK, DTRK, dlt,
        DIN, DIN, DTRK, dt_proj_b + (size_t)i * DIN);
    // selective scan + gating -> yb
    scan_kernel<<<192, 256, 0, stream>>>(
        xb, dlt, xdbl, xz, A_log + (size_t)i * DIN * NS,
        Dvec + (size_t)i * DIN, yb);
    // x += yb @ out_proj^T  (2048x1536)x(768x1536)^T
    sgemm_nt<2><<<dim3(32, 12), 256, 0, stream>>>(
        yb, DIN, out_proj_w + (size_t)i * DD * DIN, DIN, x, DD, DD, DIN,
        nullptr);
  }

  // logits = x @ W_out^T + b  (2048x768)x(32000x768)^T
  sgemm_nt<3><<<dim3(32, 500), 256, 0, stream>>>(
      x, DD, W_out_w, DD, out, VV, VV, DD, W_out_b);
}

// Round 2
// 2796.412 us; speedup vs baseline: 2.2031x; 2.2031x over previous
//
#include <hip/hip_runtime.h>
#include <hip/hip_bf16.h>
#include <math.h>

// Problem constants
#define BB   2
#define LL   1024
#define DD   768
#define DIN  1536      // d_inner
#define NS   16        // d_state
#define DCV  4         // d_conv
#define DTRK 48        // dt_rank
#define NLAY 4
#define VV   32000
#define ROWS (BB*LL)   // 2048

typedef __attribute__((ext_vector_type(8))) short short8;
typedef __attribute__((ext_vector_type(4))) float f32x4;

// ---------------- elementwise / small kernels ----------------

__global__ __launch_bounds__(256) void embed_kernel(
    const int* __restrict__ tok, const float* __restrict__ emb,
    float* __restrict__ x) {
  int idx = blockIdx.x * 256 + threadIdx.x;          // 2048*768 total
  int row = idx / DD, c = idx - row * DD;
  x[idx] = emb[(size_t)tok[row] * DD + c];
}

// fp32 -> bf16, 4 elements/thread (n divisible by 4)
__global__ __launch_bounds__(256) void cvt_bf16_kernel(
    const float* __restrict__ in, __hip_bfloat16* __restrict__ out, int n4) {
  int i = blockIdx.x * 256 + threadIdx.x;
  if (i >= n4) return;
  float4 v = ((const float4*)in)[i];
  __hip_bfloat16 t0 = __float2bfloat16(v.x);
  __hip_bfloat16 t1 = __float2bfloat16(v.y);
  __hip_bfloat16 t2 = __float2bfloat16(v.z);
  __hip_bfloat16 t3 = __float2bfloat16(v.w);
  ushort4 pack = make_ushort4(*(unsigned short*)&t0, *(unsigned short*)&t1,
                              *(unsigned short*)&t2, *(unsigned short*)&t3);
  ((ushort4*)out)[i] = pack;
}

__global__ __launch_bounds__(256) void rmsnorm_kernel(
    const float* __restrict__ x, const float* __restrict__ w,
    __hip_bfloat16* __restrict__ xn) {
  int row = blockIdx.x;
  int t = threadIdx.x;
  const float* xr = x + (size_t)row * DD;
  float v0 = xr[t], v1 = xr[t + 256], v2 = xr[t + 512];
  float ss = v0 * v0 + v1 * v1 + v2 * v2;
#pragma unroll
  for (int off = 32; off > 0; off >>= 1) ss += __shfl_down(ss, off);
  __shared__ float sred[4];
  if ((t & 63) == 0) sred[t >> 6] = ss;
  __syncthreads();
  float tot = sred[0] + sred[1] + sred[2] + sred[3];
  float scale = rsqrtf(tot * (1.0f / DD) + 1e-5f);
  __hip_bfloat16* xo = xn + (size_t)row * DD;
  xo[t]       = __float2bfloat16(v0 * scale * w[t]);
  xo[t + 256] = __float2bfloat16(v1 * scale * w[t + 256]);
  xo[t + 512] = __float2bfloat16(v2 * scale * w[t + 512]);
}

// causal depthwise conv (DC=4) + bias + silu; input = first DIN cols of xz
__global__ __launch_bounds__(256) void conv_silu_kernel(
    const float* __restrict__ xz, const float* __restrict__ cw,
    const float* __restrict__ cb, float* __restrict__ xb) {
  int idx = blockIdx.x * 256 + threadIdx.x;          // 2048*1536 total
  int row = idx / DIN;                               // b*L + l
  int d = idx - row * DIN;
  int l = row & (LL - 1);
  const float* col = xz + (size_t)row * (2 * DIN) + d;
  float w0 = cw[d * 4 + 0], w1 = cw[d * 4 + 1], w2 = cw[d * 4 + 2],
        w3 = cw[d * 4 + 3];
  float acc = cb[d] + w3 * col[0];
  if (l >= 1) acc += w2 * col[-(2 * DIN)];
  if (l >= 2) acc += w1 * col[-2 * (2 * DIN)];
  if (l >= 3) acc += w0 * col[-3 * (2 * DIN)];
  float sig = 1.0f / (1.0f + __expf(-acc));
  xb[idx] = acc * sig;
}

// ---------------- fp32 GEMM (small shapes: x_proj, dt_proj) ----------------
// C(M x N) = A(M x K) * W(N x K)^T.  EPI: 0 = none, 1 = softplus(acc+bias[n])
__device__ __forceinline__ float softplus_f(float t) {
  return t > 20.0f ? t : log1pf(__expf(t));
}

template <int EPI>
__global__ __launch_bounds__(256) void sgemm_nt(
    const float* __restrict__ A, int lda,
    const float* __restrict__ W, int ldw,
    float* __restrict__ C, int ldc,
    int N, int K, const float* __restrict__ bias) {
  __shared__ float As[16][68];
  __shared__ float Ws[16][68];
  const int tid = threadIdx.x;
  const int tx = tid & 15, ty = tid >> 4;
  const int bm = blockIdx.x, bn = blockIdx.y;
  const int lrow = tid >> 2;          // 0..63
  const int lk4 = (tid & 3) << 2;     // 0,4,8,12
  const float* Aptr = A + (size_t)(bm * 64 + lrow) * lda + lk4;
  const int wrow = bn * 64 + lrow;
  const float* Wptr = W + (size_t)wrow * ldw + lk4;
  const bool wvalid = wrow < N;
  float c[4][4] = {};
  for (int k0 = 0; k0 < K; k0 += 16) {
    float4 a4 = *(const float4*)(Aptr + k0);
    float4 w4 = wvalid ? *(const float4*)(Wptr + k0) : make_float4(0, 0, 0, 0);
    __syncthreads();
    As[lk4 + 0][lrow] = a4.x; As[lk4 + 1][lrow] = a4.y;
    As[lk4 + 2][lrow] = a4.z; As[lk4 + 3][lrow] = a4.w;
    Ws[lk4 + 0][lrow] = w4.x; Ws[lk4 + 1][lrow] = w4.y;
    Ws[lk4 + 2][lrow] = w4.z; Ws[lk4 + 3][lrow] = w4.w;
    __syncthreads();
#pragma unroll
    for (int k = 0; k < 16; k++) {
      float4 a = *(const float4*)&As[k][ty << 2];
      float4 w = *(const float4*)&Ws[k][tx << 2];
      c[0][0] += a.x * w.x; c[0][1] += a.x * w.y; c[0][2] += a.x * w.z; c[0][3] += a.x * w.w;
      c[1][0] += a.y * w.x; c[1][1] += a.y * w.y; c[1][2] += a.y * w.z; c[1][3] += a.y * w.w;
      c[2][0] += a.z * w.x; c[2][1] += a.z * w.y; c[2][2] += a.z * w.z; c[2][3] += a.z * w.w;
      c[3][0] += a.w * w.x; c[3][1] += a.w * w.y; c[3][2] += a.w * w.z; c[3][3] += a.w * w.w;
    }
  }
  const int m0 = bm * 64 + (ty << 2);
  const int n0 = bn * 64 + (tx << 2);
#pragma unroll
  for (int i = 0; i < 4; i++) {
    float* crow = C + (size_t)(m0 + i) * ldc;
#pragma unroll
    for (int j = 0; j < 4; j++) {
      int n = n0 + j;
      if (n < N) {
        float v = c[i][j];
        if constexpr (EPI == 1) v = softplus_f(v + bias[n]);
        crow[n] = v;
      }
    }
  }
}

// ---------------- bf16 MFMA GEMM (m97 structure) ----------------
// C(M x N) = A(M x K)_bf16 * W(N x K)_bf16^T, fp32 out.
// 128x128 tile, BK=32, global_load_lds 16B staging, 4 waves as 2x2 of 64x64.
// Requires: M,N multiples of 128; K multiple of 32; lda/ldw multiples of 8.
// EPI: 0 = none, 2 = C += acc (residual), 3 = acc + bias[n]

__device__ __forceinline__ void gload16(const void* g, void* l) {
  __builtin_amdgcn_global_load_lds(
      (const __attribute__((address_space(1))) void*)g,
      (__attribute__((address_space(3))) void*)l, 16, 0, 0);
}

template <int EPI>
__global__ __launch_bounds__(256) void bgemm_nt(
    const __hip_bfloat16* __restrict__ A, int lda,
    const __hip_bfloat16* __restrict__ W, int ldw,
    float* __restrict__ C, int ldc,
    int K, const float* __restrict__ bias) {
  __shared__ short As[128 * 32];   // 8 KB
  __shared__ short Ws[128 * 32];   // 8 KB
  const int tid = threadIdx.x;
  const int wave = tid >> 6, lane = tid & 63;
  const int wm = wave >> 1, wn = wave & 1;
  const int tileM = blockIdx.x * 128, tileN = blockIdx.y * 128;

  const short* Ag = (const short*)A;
  const short* Wg = (const short*)W;
  // staging: chunk cid covers A-tile row cid>>2, bf16 cols [(cid&3)*8, +8)
  const int cid0 = tid, cid1 = tid + 256;
  const size_t aOff0 = (size_t)(tileM + (cid0 >> 2)) * lda + (cid0 & 3) * 8;
  const size_t aOff1 = (size_t)(tileM + (cid1 >> 2)) * lda + (cid1 & 3) * 8;
  const size_t wOff0 = (size_t)(tileN + (cid0 >> 2)) * ldw + (cid0 & 3) * 8;
  const size_t wOff1 = (size_t)(tileN + (cid1 >> 2)) * ldw + (cid1 & 3) * 8;
  // LDS dst: wave-uniform base + lane*16B (implicit)
  short* AsD0 = As + wave * 512;
  short* AsD1 = As + 2048 + wave * 512;
  short* WsD0 = Ws + wave * 512;
  short* WsD1 = Ws + 2048 + wave * 512;

  const int fr = lane & 15, fq = lane >> 4;
  f32x4 acc[4][4] = {};

  for (int k0 = 0; k0 < K; k0 += 32) {
    gload16(Ag + aOff0 + k0, AsD0);
    gload16(Ag + aOff1 + k0, AsD1);
    gload16(Wg + wOff0 + k0, WsD0);
    gload16(Wg + wOff1 + k0, WsD1);
    __syncthreads();                    // drains vmcnt -> LDS visible
    short8 afr[4], bfr[4];
#pragma unroll
    for (int t = 0; t < 4; t++) {
      afr[t] = *(const short8*)(As + (wm * 64 + t * 16 + fr) * 32 + fq * 8);
      bfr[t] = *(const short8*)(Ws + (wn * 64 + t * 16 + fr) * 32 + fq * 8);
    }
#pragma unroll
    for (int mt = 0; mt < 4; mt++)
#pragma unroll
      for (int nt = 0; nt < 4; nt++)
        acc[mt][nt] = __builtin_amdgcn_mfma_f32_16x16x32_bf16(
            afr[mt], bfr[nt], acc[mt][nt], 0, 0, 0);
    __syncthreads();                    // LDS reads done before next stage
  }

  // C/D layout: col = lane&15, row = (lane>>4)*4 + reg
#pragma unroll
  for (int mt = 0; mt < 4; mt++) {
#pragma unroll
    for (int r = 0; r < 4; r++) {
      int row = tileM + wm * 64 + mt * 16 + fq * 4 + r;
      float* crow = C + (size_t)row * ldc;
#pragma unroll
      for (int nt = 0; nt < 4; nt++) {
        int col = tileN + wn * 64 + nt * 16 + fr;
        float v = acc[mt][nt][r];
        if constexpr (EPI == 2) v += crow[col];
        else if constexpr (EPI == 3) v += bias[col];
        crow[col] = v;
      }
    }
  }
}

// ---------------- selective scan ----------------
// One wave per block; wave handles 4 channels (sub=lane/16), 16 states each.
__global__ __launch_bounds__(64) void scan_kernel(
    const float* __restrict__ u,      // xb   (2048 x 1536)
    const float* __restrict__ dlt,    // delta(2048 x 1536)
    const float* __restrict__ xdbl,   // (2048 x 80): B at +48, C at +64
    const float* __restrict__ xz,     // z at col DIN+d, stride 2*DIN
    const float* __restrict__ A_log,  // layer slice (1536 x 16)
    const float* __restrict__ Dv,     // layer slice (1536)
    __hip_bfloat16* __restrict__ y) { // (2048 x 1536) bf16
  int lane = threadIdx.x;
  int n = lane & 15;
  int sub = lane >> 4;
  int p = blockIdx.x * 4 + sub;       // 0..3071 (b,d) pair
  int b = p / DIN;
  int d = p - b * DIN;
  float Ac = -__expf(A_log[d * NS + n]);
  float Dd = Dv[d];
  const float* urow = u + (size_t)b * LL * DIN + d;
  const float* drow = dlt + (size_t)b * LL * DIN + d;
  const float* brow = xdbl + (size_t)b * LL * 80 + DTRK + n;
  const float* crow = xdbl + (size_t)b * LL * 80 + DTRK + NS + n;
  const float* zrow = xz + (size_t)b * LL * (2 * DIN) + DIN + d;
  __hip_bfloat16* yrow = y + (size_t)b * LL * DIN + d;
  float h = 0.0f;
  // 1-deep software pipeline so loads overlap the exp/fma chain
  float dl = drow[0], ul = urow[0], bl = brow[0], cl = crow[0], zl = zrow[0];
  for (int l = 0; l < LL; l++) {
    float dn = 0, un = 0, bn = 0, cn = 0, zn = 0;
    if (l + 1 < LL) {
      size_t o = (size_t)(l + 1);
      dn = drow[o * DIN]; un = urow[o * DIN];
      bn = brow[o * 80];  cn = crow[o * 80];
      zn = zrow[o * (2 * DIN)];
    }
    h = __expf(dl * Ac) * h + dl * bl * ul;
    float yp = h * cl;
    yp += __shfl_xor(yp, 1);
    yp += __shfl_xor(yp, 2);
    yp += __shfl_xor(yp, 4);
    yp += __shfl_xor(yp, 8);
    if (n == 0) {
      float sig = 1.0f / (1.0f + __expf(-zl));
      yrow[(size_t)l * DIN] = __float2bfloat16((yp + ul * Dd) * (zl * sig));
    }
    dl = dn; ul = un; bl = bn; cl = cn; zl = zn;
  }
}

// ---------------- launch ----------------

extern "C" void kernel_launch(void* const* d_in, const int* in_sizes, int n_in,
                              void* d_out, int out_size, void* d_ws,
                              size_t ws_size, hipStream_t stream) {
  const int*   tokens    = (const int*)d_in[0];
  const float* embedding = (const float*)d_in[1];
  const float* W_out_w   = (const float*)d_in[2];
  const float* W_out_b   = (const float*)d_in[3];
  const float* norm_w    = (const float*)d_in[4];
  const float* in_proj_w = (const float*)d_in[5];
  const float* conv_w    = (const float*)d_in[6];
  const float* conv_b    = (const float*)d_in[7];
  const float* x_proj_w  = (const float*)d_in[8];
  const float* dt_proj_w = (const float*)d_in[9];
  const float* dt_proj_b = (const float*)d_in[10];
  const float* A_log     = (const float*)d_in[11];
  const float* Dvec      = (const float*)d_in[12];
  const float* out_proj_w= (const float*)d_in[13];
  float* out = (float*)d_out;

  float* ws = (float*)d_ws;
  float* x    = ws;                          // 2048*768
  float* xz   = x + (size_t)ROWS * DD;       // 2048*3072
  float* xb   = xz + (size_t)ROWS * 2 * DIN; // 2048*1536
  float* xdbl = xb + (size_t)ROWS * DIN;     // 2048*80
  float* dlt  = xdbl + (size_t)ROWS * 80;    // 2048*1536
  __hip_bfloat16* bfbase = (__hip_bfloat16*)(dlt + (size_t)ROWS * DIN);
  __hip_bfloat16* xnb  = bfbase;                         // 2048*768
  __hip_bfloat16* ybb  = xnb + (size_t)ROWS * DD;        // 2048*1536
  __hip_bfloat16* xbf  = ybb + (size_t)ROWS * DIN;       // 2048*768
  __hip_bfloat16* wInB = xbf + (size_t)ROWS * DD;        // 4*3072*768
  __hip_bfloat16* wOpB = wInB + (size_t)NLAY * 2 * DIN * DD; // 4*768*1536
  __hip_bfloat16* wLgB = wOpB + (size_t)NLAY * DD * DIN; // 32000*768

  // weight conversions (every call; same work each call)
  {
    int n4 = NLAY * 2 * DIN * DD / 4;
    cvt_bf16_kernel<<<(n4 + 255) / 256, 256, 0, stream>>>(in_proj_w, wInB, n4);
    n4 = NLAY * DD * DIN / 4;
    cvt_bf16_kernel<<<(n4 + 255) / 256, 256, 0, stream>>>(out_proj_w, wOpB, n4);
    n4 = VV * DD / 4;
    cvt_bf16_kernel<<<(n4 + 255) / 256, 256, 0, stream>>>(W_out_w, wLgB, n4);
  }

  embed_kernel<<<ROWS * DD / 256, 256, 0, stream>>>(tokens, embedding, x);

  for (int i = 0; i < NLAY; i++) {
    rmsnorm_kernel<<<ROWS, 256, 0, stream>>>(x, norm_w + (size_t)i * DD, xnb);
    // xz = xn @ in_proj^T   (2048x768)x(3072x768)^T  [bf16 MFMA]
    bgemm_nt<0><<<dim3(16, 24), 256, 0, stream>>>(
        xnb, DD, wInB + (size_t)i * 2 * DIN * DD, DD, xz, 2 * DIN, DD,
        nullptr);
    // xb = silu(conv(xz[:, :DIN]))
    conv_silu_kernel<<<ROWS * DIN / 256, 256, 0, stream>>>(
        xz, conv_w + (size_t)i * DIN * DCV, conv_b + (size_t)i * DIN, xb);
    // x_dbl = xb @ x_proj^T (2048x1536)x(80x1536)^T  [fp32]
    sgemm_nt<0><<<dim3(32, 2), 256, 0, stream>>>(
        xb, DIN, x_proj_w + (size_t)i * (DTRK + 2 * NS) * DIN, DIN, xdbl,
        DTRK + 2 * NS, DTRK + 2 * NS, DIN, nullptr);
    // delta = softplus(dt @ dt_proj^T + dt_b) (2048x48)x(1536x48)^T [fp32]
    sgemm_nt<1><<<dim3(32, 24), 256, 0, stream>>>(
        xdbl, DTRK + 2 * NS, dt_proj_w + (size_t)i * DIN * DTRK, DTRK, dlt,
        DIN, DIN, DTRK, dt_proj_b + (size_t)i * DIN);
    // selective scan + gating -> ybb (bf16)
    scan_kernel<<<768, 64, 0, stream>>>(
        xb, dlt, xdbl, xz, A_log + (size_t)i * DIN * NS,
        Dvec + (size_t)i * DIN, ybb);
    // x += yb @ out_proj^T  (2048x1536)x(768x1536)^T  [bf16 MFMA]
    bgemm_nt<2><<<dim3(16, 6), 256, 0, stream>>>(
        ybb, DIN, wOpB + (size_t)i * DD * DIN, DIN, x, DD, DIN, nullptr);
  }

  // logits = x @ W_out^T + b  (2048x768)x(32000x768)^T  [bf16 MFMA]
  {
    int n4 = ROWS * DD / 4;
    cvt_bf16_kernel<<<(n4 + 255) / 256, 256, 0, stream>>>(x, xbf, n4);
  }
  bgemm_nt<3><<<dim3(16, 250), 256, 0, stream>>>(
      xbf, DD, wLgB, DD, out, VV, DD, W_out_b);
}